// Round 1
// baseline (1690.552 us; speedup 1.0000x reference)
//
#include <hip/hip_runtime.h>

// Problem constants (B=1 fixed)
#define CC   32
#define DD   24
#define HH   96
#define WW   96
#define HWC  (HH*WW)        // 9216
#define DHW  (DD*HH*WW)     // 221184
#define NG   4
#define CPG  (CC/NG)        // 8
#define OC1  54
#define GN_EPS 1e-5f

// ---------------- weight transpose: src[o][c][tap] -> dst[(c*27+tap)*O + o] ----------------
__global__ void transpose_w(const float* __restrict__ src, float* __restrict__ dst,
                            int O, int n) {
    int idx = blockIdx.x * 256 + threadIdx.x;
    if (idx >= n) return;
    int o    = idx % O;
    int rest = idx / O;
    int tap  = rest % 27;
    int c    = rest / 27;
    dst[idx] = src[(o * CC + c) * 27 + tap];
}

// ---------------- group-norm stats: sum & sumsq per group ----------------
__global__ void gn_stats(const float* __restrict__ x, float* __restrict__ stats) {
    // grid = NG*32 blocks, 256 threads
    const int g = blockIdx.x >> 5;
    const int s = blockIdx.x & 31;
    const float4* base = (const float4*)(x + (size_t)g * CPG * DHW);
    const int n4 = CPG * DHW / 4;  // 442368
    float s1 = 0.f, s2 = 0.f;
    for (int idx = s * 256 + threadIdx.x; idx < n4; idx += 32 * 256) {
        float4 v = base[idx];
        s1 += v.x + v.y + v.z + v.w;
        s2 += v.x * v.x + v.y * v.y + v.z * v.z + v.w * v.w;
    }
    // wave64 reduce
    for (int off = 32; off > 0; off >>= 1) {
        s1 += __shfl_down(s1, off);
        s2 += __shfl_down(s2, off);
    }
    __shared__ float ls1[4], ls2[4];
    int wid = threadIdx.x >> 6;
    if ((threadIdx.x & 63) == 0) { ls1[wid] = s1; ls2[wid] = s2; }
    __syncthreads();
    if (threadIdx.x == 0) {
        float a = 0.f, b = 0.f;
        for (int i = 0; i < 4; i++) { a += ls1[i]; b += ls2[i]; }
        atomicAdd(&stats[g * 2 + 0], a);
        atomicAdd(&stats[g * 2 + 1], b);
    }
}

// ---------------- group-norm apply + relu (float4) ----------------
__global__ void gn_apply(const float* __restrict__ x, const float* __restrict__ stats,
                         const float* __restrict__ gamma, const float* __restrict__ beta,
                         float* __restrict__ y) {
    int idx = blockIdx.x * 256 + threadIdx.x;   // float4 index
    const int n4 = CC * DHW / 4;
    if (idx >= n4) return;
    const int c = idx / (DHW / 4);
    const int g = c >> 3;
    const float invN = 1.0f / (float)(CPG * DHW);
    float mean = stats[2 * g] * invN;
    float var  = stats[2 * g + 1] * invN - mean * mean;
    float rstd = rsqrtf(var + GN_EPS);
    float ga = gamma[c] * rstd;
    float be = beta[c] - mean * ga;
    float4 v = ((const float4*)x)[idx];
    float4 r;
    r.x = fmaxf(0.f, v.x * ga + be);
    r.y = fmaxf(0.f, v.y * ga + be);
    r.z = fmaxf(0.f, v.z * ga + be);
    r.w = fmaxf(0.f, v.w * ga + be);
    ((float4*)y)[idx] = r;
}

// ---------------- dense 3x3x3 conv, 32 -> 54 channels, pad 1 in all dims ----------------
// wT layout: [(c*27 + i*9+j*3+k)*54 + o]
__global__ __launch_bounds__(192) void offs_conv(const float* __restrict__ xin,
                                                 const float* __restrict__ wT,
                                                 const float* __restrict__ bias,
                                                 float* __restrict__ outp) {
    const int t = threadIdx.x;
    const int r = blockIdx.x * 2 + (t / 96);   // row index in [0, D*H)
    const int w = t % 96;
    const int d = r / HH;
    const int h = r % HH;
    const int p = r * WW + w;

    float acc[OC1];
#pragma unroll
    for (int o = 0; o < OC1; o++) acc[o] = 0.f;

#pragma unroll 1
    for (int c = 0; c < CC; c++) {
        const float* xc = xin + (size_t)c * DHW;
#pragma unroll 1
        for (int i = 0; i < 3; i++) {
            const int dd = d + i - 1;
            if (dd < 0 || dd >= DD) continue;
#pragma unroll 1
            for (int j = 0; j < 3; j++) {
                const int hh2 = h + j - 1;
                if (hh2 < 0 || hh2 >= HH) continue;
                const float* row = xc + dd * HWC + hh2 * WW;
                const float x0 = (w >= 1)     ? row[w - 1] : 0.f;
                const float x1 = row[w];
                const float x2 = (w + 1 < WW) ? row[w + 1] : 0.f;
                const float* wp = wT + (c * 27 + i * 9 + j * 3) * OC1;
#pragma unroll
                for (int o = 0; o < OC1; o++) acc[o] = fmaf(x0, wp[o], acc[o]);
#pragma unroll
                for (int o = 0; o < OC1; o++) acc[o] = fmaf(x1, wp[OC1 + o], acc[o]);
#pragma unroll
                for (int o = 0; o < OC1; o++) acc[o] = fmaf(x2, wp[2 * OC1 + o], acc[o]);
            }
        }
    }
#pragma unroll
    for (int o = 0; o < OC1; o++) outp[(size_t)o * DHW + p] = acc[o] + bias[o];
}

// ---------------- deformable conv (H/W bilinear, D shift with zero pad) ----------------
// wT layout: [(c*27 + tap)*32 + o]; off layout: [54][DHW], channel tap*2+{0,1}
__global__ __launch_bounds__(192) void deform_conv(const float* __restrict__ xin,
                                                   const float* __restrict__ off,
                                                   const float* __restrict__ wT,
                                                   const float* __restrict__ bias,
                                                   const float* __restrict__ resid,
                                                   float* __restrict__ outp) {
    const int t = threadIdx.x;
    const int r = blockIdx.x * 2 + (t / 96);
    const int w = t % 96;
    const int d = r / HH;
    const int h = r % HH;
    const int p = r * WW + w;

    float acc[CC];
#pragma unroll
    for (int o = 0; o < CC; o++) acc[o] = 0.f;

#pragma unroll 1
    for (int i = 0; i < 3; i++) {
        const int dd = d + i - 1;
        if (dd < 0 || dd >= DD) continue;   // zero-padded depth -> zero contribution
        const float* xd = xin + dd * HWC;
#pragma unroll 1
        for (int jk = 0; jk < 9; jk++) {
            const int j = jk / 3;
            const int k = jk % 3;
            const int tap = i * 9 + jk;
            const float oh  = off[(size_t)(tap * 2 + 0) * DHW + p];
            const float owv = off[(size_t)(tap * 2 + 1) * DHW + p];
            const float hp  = (float)(h + j - 1) + oh;
            const float wpf = (float)(w + k - 1) + owv;
            const float h0f = floorf(hp), w0f = floorf(wpf);
            const int h0 = (int)h0f, w0 = (int)w0f;
            const float lh = hp - h0f, lw = wpf - w0f;
            const bool hv0 = (h0 >= 0) && (h0 < HH);
            const bool hv1 = (h0 >= -1) && (h0 < HH - 1);
            const bool wv0 = (w0 >= 0) && (w0 < WW);
            const bool wv1 = (w0 >= -1) && (w0 < WW - 1);
            const float c00 = (hv0 && wv0) ? (1.f - lh) * (1.f - lw) : 0.f;
            const float c01 = (hv0 && wv1) ? (1.f - lh) * lw : 0.f;
            const float c10 = (hv1 && wv0) ? lh * (1.f - lw) : 0.f;
            const float c11 = (hv1 && wv1) ? lh * lw : 0.f;
            const int h0c = min(max(h0, 0), HH - 1);
            const int h1c = min(max(h0 + 1, 0), HH - 1);
            const int w0c = min(max(w0, 0), WW - 1);
            const int w1c = min(max(w0 + 1, 0), WW - 1);
            const int i00 = h0c * WW + w0c;
            const int i01 = h0c * WW + w1c;
            const int i10 = h1c * WW + w0c;
            const int i11 = h1c * WW + w1c;
#pragma unroll 4
            for (int c = 0; c < CC; c++) {
                const float* bc = xd + (size_t)c * DHW;
                const float val = c00 * bc[i00] + c01 * bc[i01]
                                + c10 * bc[i10] + c11 * bc[i11];
                const float* wpp = wT + (c * 27 + tap) * CC;
#pragma unroll
                for (int o = 0; o < CC; o++) acc[o] = fmaf(val, wpp[o], acc[o]);
            }
        }
    }
    if (resid) {
#pragma unroll
        for (int o = 0; o < CC; o++)
            outp[(size_t)o * DHW + p] = acc[o] + bias[o] + resid[(size_t)o * DHW + p];
    } else {
#pragma unroll
        for (int o = 0; o < CC; o++)
            outp[(size_t)o * DHW + p] = acc[o] + bias[o];
    }
}

extern "C" void kernel_launch(void* const* d_in, const int* in_sizes, int n_in,
                              void* d_out, int out_size, void* d_ws, size_t ws_size,
                              hipStream_t stream) {
    const float* x   = (const float*)d_in[0];
    const float* g1  = (const float*)d_in[1];
    const float* be1 = (const float*)d_in[2];
    const float* g2  = (const float*)d_in[3];
    const float* be2 = (const float*)d_in[4];
    const float* ow1 = (const float*)d_in[5];
    const float* ob1 = (const float*)d_in[6];
    const float* dw1 = (const float*)d_in[7];
    const float* db1 = (const float*)d_in[8];
    const float* ow2 = (const float*)d_in[9];
    const float* ob2 = (const float*)d_in[10];
    const float* dw2 = (const float*)d_in[11];
    const float* db2 = (const float*)d_in[12];
    float* out = (float*)d_out;
    float* ws  = (float*)d_ws;

    // ws layout (in floats)
    float* stats = ws;                 // 16 (zeroed each call)
    float* wT1   = ws + 256;           // 46656
    float* dwT1  = ws + 47104;         // 27648
    float* wT2   = ws + 74752;         // 46656
    float* dwT2  = ws + 121600;        // 27648
    float* h1    = ws + 149504;        // 7077888  (reused for h2)
    float* off1  = ws + 7227392;       // 11943936 (reused for off2)
    // deform1 output goes to d_out (reused as scratch, overwritten by deform2)

    hipMemsetAsync(stats, 0, 16 * sizeof(float), stream);
    transpose_w<<<(54 * 32 * 27 + 255) / 256, 256, 0, stream>>>(ow1, wT1, 54, 54 * 32 * 27);
    transpose_w<<<(32 * 32 * 27 + 255) / 256, 256, 0, stream>>>(dw1, dwT1, 32, 32 * 32 * 27);
    transpose_w<<<(54 * 32 * 27 + 255) / 256, 256, 0, stream>>>(ow2, wT2, 54, 54 * 32 * 27);
    transpose_w<<<(32 * 32 * 27 + 255) / 256, 256, 0, stream>>>(dw2, dwT2, 32, 32 * 32 * 27);

    // block 1
    gn_stats<<<NG * 32, 256, 0, stream>>>(x, stats + 0);
    gn_apply<<<(CC * DHW / 4 + 255) / 256, 256, 0, stream>>>(x, stats + 0, g1, be1, h1);
    offs_conv<<<DD * HH / 2, 192, 0, stream>>>(h1, wT1, ob1, off1);
    deform_conv<<<DD * HH / 2, 192, 0, stream>>>(h1, off1, dwT1, db1, nullptr, out);

    // block 2 (input = deform1 output currently living in d_out)
    gn_stats<<<NG * 32, 256, 0, stream>>>(out, stats + 8);
    gn_apply<<<(CC * DHW / 4 + 255) / 256, 256, 0, stream>>>(out, stats + 8, g2, be2, h1);
    offs_conv<<<DD * HH / 2, 192, 0, stream>>>(h1, wT2, ob2, off1);
    deform_conv<<<DD * HH / 2, 192, 0, stream>>>(h1, off1, dwT2, db2, x, out);
}